// Round 1
// baseline (1459.748 us; speedup 1.0000x reference)
//
#include <hip/hip_runtime.h>

// ---------------------------------------------------------------------------
// GraphGridCrossAttnModel — fp32 round-0 implementation.
// B=4 T=24 N=2048 DG=64 E=128 NH=4 HD=32 H=W=64 P=8 -> NP=64
// Key identities used (exact):
//  * k-path fold:  k = relu(x@w1+b1) @ (w2@kw) + (b2@kw+kb)
//  * s via Pk:     s[hq,i] = hidden_k_i . Pk[:,hq] + ck[hq],  Pk = Wk[:,hslice]@q/sqrt(HD)
//  * v-path fold:  o = (sum_i a_i * hidden_v_i) @ (Wv[:,hslice]@ow) + (bv@ow+ob)
//  * outputs are lerps of 24 rows: g_out = interp(og_g), up = interp(og_r@up_w)+b
// ---------------------------------------------------------------------------

constexpr int   BB   = 4;
constexpr int   TT   = 24;
constexpr int   KLGc = 49152;   // T*N
constexpr int   KLRc = 1536;    // T*NP
constexpr float INV_SCALE = 0.17677669529663687f;   // 1/sqrt(32)

// ---------------- small precompute kernels ----------------------------------

__global__ __launch_bounds__(128) void k_te(const float* __restrict__ tidx,
    const float* __restrict__ w1, const float* __restrict__ b1,
    const float* __restrict__ w2, const float* __restrict__ b2,
    float* __restrict__ te) {
  int row = blockIdx.x, e = threadIdx.x;
  __shared__ float h[128];
  float tv = tidx[row];
  h[e] = fmaxf(tv * w1[e] + b1[e], 0.f);
  __syncthreads();
  float acc = b2[e];
  for (int j = 0; j < 128; ++j) acc += h[j] * w2[j * 128 + e];
  te[row * 128 + e] = acc;
}

__global__ __launch_bounds__(128) void k_q(const float* __restrict__ te,
    const float* __restrict__ wg, const float* __restrict__ bg,
    const float* __restrict__ wr, const float* __restrict__ br,
    float* __restrict__ qg, float* __restrict__ qr) {
  int row = blockIdx.x, e = threadIdx.x;
  const float* w = blockIdx.y ? wr : wg;
  const float* bb = blockIdx.y ? br : bg;
  float* out = blockIdx.y ? qr : qg;
  __shared__ float x[128];
  x[e] = te[row * 128 + e];
  __syncthreads();
  float acc = bb[e];
  for (int j = 0; j < 128; ++j) acc += x[j] * w[j * 128 + e];
  out[row * 128 + e] = acc;
}

// W = A@B (+ bias row j==128: Ob = Ab@B + Bb)
__global__ __launch_bounds__(128) void k_fold(
    const float* A0, const float* Ab0, const float* B0, const float* Bb0, float* O0, float* Ob0,
    const float* A1, const float* Ab1, const float* B1, const float* Bb1, float* O1, float* Ob1,
    const float* A2, const float* Ab2, const float* B2, const float* Bb2, float* O2, float* Ob2,
    const float* A3, const float* Ab3, const float* B3, const float* Bb3, float* O3, float* Ob3) {
  int task = blockIdx.y, j = blockIdx.x, e = threadIdx.x;
  const float *A, *Ab, *Bm, *Bb; float *O, *Ob;
  switch (task) {
    case 0: A=A0; Ab=Ab0; Bm=B0; Bb=Bb0; O=O0; Ob=Ob0; break;
    case 1: A=A1; Ab=Ab1; Bm=B1; Bb=Bb1; O=O1; Ob=Ob1; break;
    case 2: A=A2; Ab=Ab2; Bm=B2; Bb=Bb2; O=O2; Ob=Ob2; break;
    default:A=A3; Ab=Ab3; Bm=B3; Bb=Bb3; O=O3; Ob=Ob3; break;
  }
  __shared__ float a[128];
  a[e] = (j < 128) ? A[j * 128 + e] : Ab[e];
  __syncthreads();
  float acc = (j < 128) ? 0.f : Bb[e];
  for (int m = 0; m < 128; ++m) acc += a[m] * Bm[m * 128 + e];
  if (j < 128) O[j * 128 + e] = acc; else Ob[e] = acc;
}

// Wvo[h][j][e] = sum_d Wv[j][h*32+d]*ow[(h*32+d)*128+e]; bvo = bv@ow + ob
__global__ __launch_bounds__(128) void k_wvo(
    const float* Wv_g, const float* bv_g, const float* ow_g, const float* ob_g, float* Wvo_g, float* bvo_g,
    const float* Wv_r, const float* bv_r, const float* ow_r, const float* ob_r, float* Wvo_r, float* bvo_r) {
  int j = blockIdx.x, e = threadIdx.x;
  int br = blockIdx.y >> 2, h = blockIdx.y & 3;
  const float* Wv = br ? Wv_r : Wv_g;  const float* bv = br ? bv_r : bv_g;
  const float* ow = br ? ow_r : ow_g;  const float* ob = br ? ob_r : ob_g;
  float* Wvo = br ? Wvo_r : Wvo_g;     float* bvo = br ? bvo_r : bvo_g;
  if (j < 128) {
    __shared__ float wrow[32];
    if (e < 32) wrow[e] = Wv[j * 128 + h * 32 + e];
    __syncthreads();
    float acc = 0.f;
    for (int d = 0; d < 32; ++d) acc += wrow[d] * ow[(h * 32 + d) * 128 + e];
    Wvo[(h * 128 + j) * 128 + e] = acc;
  } else if (h == 0) {
    __shared__ float bbv[128];
    bbv[e] = bv[e];
    __syncthreads();
    float acc = ob[e];
    for (int m = 0; m < 128; ++m) acc += bbv[m] * ow[m * 128 + e];
    bvo[e] = acc;
  }
}

// Pk[b][j][hq] = INV_SCALE * sum_d Wk[j][h*32+d]*q[b,t][h*32+d]; j==128 -> ck
__global__ __launch_bounds__(128) void k_pk(
    const float* Wk_g, const float* bk_g, const float* q_g, float* Pk_g, float* ck_g,
    const float* Wk_r, const float* bk_r, const float* q_r, float* Pk_r, float* ck_r) {
  int j = blockIdx.x;
  int br = blockIdx.y >> 2, b = blockIdx.y & 3;
  int hq = threadIdx.x;
  if (hq >= 96) return;
  const float* Wk = br ? Wk_r : Wk_g;  const float* bk = br ? bk_r : bk_g;
  const float* q  = br ? q_r  : q_g;
  float* Pk = br ? Pk_r : Pk_g;        float* ck = br ? ck_r : ck_g;
  int h = hq / 24, t = hq % 24;
  const float* qrow = q + (b * 24 + t) * 128 + h * 32;
  if (j < 128) {
    const float* wrow = Wk + j * 128 + h * 32;
    float acc = 0.f;
    for (int d = 0; d < 32; ++d) acc += wrow[d] * qrow[d];
    Pk[(b * 128 + j) * 96 + hq] = acc * INV_SCALE;
  } else {
    float acc = 0.f;
    for (int d = 0; d < 32; ++d) acc += bk[h * 32 + d] * qrow[d];
    ck[b * 96 + hq] = acc * INV_SCALE;
  }
}

// peT[k][o] = pe_w[o][k]   (pe_w viewed as 128 x 8192)
__global__ __launch_bounds__(256) void k_transpose(const float* __restrict__ pw,
                                                   float* __restrict__ peT) {
  __shared__ float tile[32][33];
  int kb = blockIdx.x * 32, ob = blockIdx.y * 32;
  int tx = threadIdx.x & 31, ty = threadIdx.x >> 5;
  for (int r = ty; r < 32; r += 8) tile[r][tx] = pw[(size_t)(ob + r) * 8192 + kb + tx];
  __syncthreads();
  for (int r = ty; r < 32; r += 8) peT[(size_t)(kb + r) * 128 + ob + tx] = tile[tx][r];
}

// ---------------- fused per-key attention (flash style, no-max softmax) -----

template <int DIN>
__device__ __forceinline__ void hidden16(const float* __restrict__ w1,
    const float* __restrict__ b1, const float* xT, int jcol, int khalf,
    float* dst, int pitch) {
  constexpr int PXT = 36;
  float h[16];
#pragma unroll
  for (int kk = 0; kk < 16; ++kk) h[kk] = 0.f;
#pragma unroll 2
  for (int m = 0; m < DIN; ++m) {
    float w = w1[m * 128 + jcol];
    const float4 x0 = *(const float4*)&xT[m * PXT + khalf * 16 + 0];
    const float4 x1 = *(const float4*)&xT[m * PXT + khalf * 16 + 4];
    const float4 x2 = *(const float4*)&xT[m * PXT + khalf * 16 + 8];
    const float4 x3 = *(const float4*)&xT[m * PXT + khalf * 16 + 12];
    h[0] += w * x0.x;  h[1] += w * x0.y;  h[2] += w * x0.z;  h[3] += w * x0.w;
    h[4] += w * x1.x;  h[5] += w * x1.y;  h[6] += w * x1.z;  h[7] += w * x1.w;
    h[8] += w * x2.x;  h[9] += w * x2.y;  h[10] += w * x2.z; h[11] += w * x2.w;
    h[12] += w * x3.x; h[13] += w * x3.y; h[14] += w * x3.z; h[15] += w * x3.w;
  }
  float bb = b1[jcol];
#pragma unroll
  for (int kk = 0; kk < 16; ++kk)
    dst[(khalf * 16 + kk) * pitch + jcol] = fmaxf(h[kk] + bb, 0.f);
}

template <int DIN>
__global__ __launch_bounds__(256) void k_flash(
    const float* __restrict__ X,
    const float* __restrict__ w1k, const float* __restrict__ b1k,
    const float* __restrict__ w1v, const float* __restrict__ b1v,
    const float* __restrict__ Pk,  const float* __restrict__ ck,
    float* __restrict__ accP, float* __restrict__ lP,
    int KL, int kpb) {
  constexpr int PXT = 36, PHK = 129, PHV = 128, PP = 97;
  int b = blockIdx.y, chunk = blockIdx.x, nchunk = gridDim.x;
  int t = threadIdx.x;
  const float* Xb  = X + (size_t)b * KL * DIN + (size_t)chunk * kpb * DIN;
  const float* Pkb = Pk + b * 128 * 96;
  const float* ckb = ck + b * 96;

  __shared__ __align__(16) float xT[DIN * PXT];
  __shared__ float hk_s[32 * PHK];
  __shared__ __align__(16) float hv_s[32 * PHV];
  __shared__ float p_s[32 * PP];

  int ti = t >> 4, tj = t & 15;
  int hq0 = ti * 6, d0 = tj * 8;
  int jcol = t & 127, khalf = t >> 7;

  float acc[6][8];
#pragma unroll
  for (int i = 0; i < 6; ++i)
#pragma unroll
    for (int j = 0; j < 8; ++j) acc[i][j] = 0.f;
  float lacc = 0.f;

  for (int s0 = 0; s0 < kpb; s0 += 32) {
    // stage 32 key rows, transposed: xT[m][key]
    for (int lin = t; lin < 32 * DIN; lin += 256) {
      int key = lin / DIN, m = lin % DIN;
      xT[m * PXT + key] = Xb[(size_t)s0 * DIN + lin];
    }
    __syncthreads();
    hidden16<DIN>(w1k, b1k, xT, jcol, khalf, hk_s, PHK);   // hidden_k
    __syncthreads();
    {  // s -> p = exp(s)  (logits are ~1e-5, no max needed)
      int k0 = 2 * tj, k1 = k0 + 1;
      float sv0[6], sv1[6];
#pragma unroll
      for (int r = 0; r < 6; ++r) { sv0[r] = ckb[hq0 + r]; sv1[r] = sv0[r]; }
#pragma unroll 2
      for (int j = 0; j < 128; ++j) {
        float h0 = hk_s[k0 * PHK + j], h1 = hk_s[k1 * PHK + j];
        const float* pkr = Pkb + j * 96 + hq0;
#pragma unroll
        for (int r = 0; r < 6; ++r) { float pv = pkr[r]; sv0[r] += h0 * pv; sv1[r] += h1 * pv; }
      }
#pragma unroll
      for (int r = 0; r < 6; ++r) {
        p_s[k0 * PP + hq0 + r] = __expf(sv0[r]);
        p_s[k1 * PP + hq0 + r] = __expf(sv1[r]);
      }
    }
    __syncthreads();
    if (t < 96) {
      float ls = 0.f;
#pragma unroll
      for (int k = 0; k < 32; ++k) ls += p_s[k * PP + t];
      lacc += ls;
    }
    hidden16<DIN>(w1v, b1v, xT, jcol, khalf, hv_s, PHV);   // hidden_v (reuses xT)
    __syncthreads();
#pragma unroll 2
    for (int k = 0; k < 32; ++k) {   // acc[hq][d] += p * hidden_v
      const float4 v0 = *(const float4*)&hv_s[k * PHV + d0];
      const float4 v1 = *(const float4*)&hv_s[k * PHV + d0 + 4];
#pragma unroll
      for (int r = 0; r < 6; ++r) {
        float pv = p_s[k * PP + hq0 + r];
        acc[r][0] += pv * v0.x; acc[r][1] += pv * v0.y; acc[r][2] += pv * v0.z; acc[r][3] += pv * v0.w;
        acc[r][4] += pv * v1.x; acc[r][5] += pv * v1.y; acc[r][6] += pv * v1.z; acc[r][7] += pv * v1.w;
      }
    }
    __syncthreads();
  }
  float* ap = accP + (size_t)(b * nchunk + chunk) * 96 * 128;
#pragma unroll
  for (int r = 0; r < 6; ++r) {
    *(float4*)&ap[(hq0 + r) * 128 + d0]     = make_float4(acc[r][0], acc[r][1], acc[r][2], acc[r][3]);
    *(float4*)&ap[(hq0 + r) * 128 + d0 + 4] = make_float4(acc[r][4], acc[r][5], acc[r][6], acc[r][7]);
  }
  if (t < 96) lP[(size_t)(b * nchunk + chunk) * 96 + t] = lacc;
}

// ---------------- patch conv (implicit GEMM, split-K) ------------------------

__global__ __launch_bounds__(256) void k_patch(const float* __restrict__ X,
    const float* __restrict__ peT, float* __restrict__ patchP) {
  int bt = blockIdx.x;      // 0..95
  int kc = blockIdx.y;      // 0..3 : K-chunk of 2048
  int t = threadIdx.x;
  const float* Xbt = X + (size_t)bt * 524288;
  __shared__ float X_s[64 * 33];
  __shared__ __align__(16) float W_s[32 * 128];
  int ti = t >> 4, tj = t & 15;   // 4 patches x 8 outs
  float acc[4][8];
#pragma unroll
  for (int i = 0; i < 4; ++i)
#pragma unroll
    for (int j = 0; j < 8; ++j) acc[i][j] = 0.f;

  for (int ks = 0; ks < 64; ++ks) {
    int kg0 = kc * 2048 + ks * 32;
    int c = kg0 >> 6, half = (kg0 >> 5) & 1;
    for (int r = 0; r < 8; ++r) {       // X tile: 64 patches x 32 k
      int lin = r * 256 + t;
      int hp = lin >> 8, off = lin & 255;
      int pl = off >> 6, wp = (off >> 3) & 7, q = off & 7;
      X_s[(hp * 8 + wp) * 33 + pl * 8 + q] =
          Xbt[(size_t)c * 4096 + (hp * 8 + half * 4 + pl) * 64 + wp * 8 + q];
    }
    for (int r = 0; r < 16; ++r) {      // W tile: 32 k x 128 o
      int lin = r * 256 + t;
      int kk = lin >> 7, o = lin & 127;
      W_s[kk * 128 + o] = peT[(size_t)(kg0 + kk) * 128 + o];
    }
    __syncthreads();
#pragma unroll 4
    for (int kk = 0; kk < 32; ++kk) {
      float4 w0 = *(const float4*)&W_s[kk * 128 + tj * 8];
      float4 w1 = *(const float4*)&W_s[kk * 128 + tj * 8 + 4];
#pragma unroll
      for (int pp = 0; pp < 4; ++pp) {
        float xv = X_s[(ti * 4 + pp) * 33 + kk];
        acc[pp][0] += xv * w0.x; acc[pp][1] += xv * w0.y; acc[pp][2] += xv * w0.z; acc[pp][3] += xv * w0.w;
        acc[pp][4] += xv * w1.x; acc[pp][5] += xv * w1.y; acc[pp][6] += xv * w1.z; acc[pp][7] += xv * w1.w;
      }
    }
    __syncthreads();
  }
  float* outp = patchP + ((size_t)kc * 6144 + bt * 64) * 128;
#pragma unroll
  for (int pp = 0; pp < 4; ++pp) {
    *(float4*)&outp[(ti * 4 + pp) * 128 + tj * 8]     = make_float4(acc[pp][0], acc[pp][1], acc[pp][2], acc[pp][3]);
    *(float4*)&outp[(ti * 4 + pp) * 128 + tj * 8 + 4] = make_float4(acc[pp][4], acc[pp][5], acc[pp][6], acc[pp][7]);
  }
}

__global__ __launch_bounds__(256) void k_reduceK(const float* __restrict__ P,
    const float* __restrict__ bias, float* __restrict__ out, int n, int nc) {
  int idx = blockIdx.x * 256 + threadIdx.x;
  if (idx >= n) return;
  float a = bias[idx & 127];
  for (int c = 0; c < nc; ++c) a += P[(size_t)c * n + idx];
  out[idx] = a;
}

__global__ __launch_bounds__(256) void k_reduceacc(const float* __restrict__ accP,
    float* __restrict__ out, int nchunk) {
  int b = blockIdx.y;
  int idx = blockIdx.x * 256 + threadIdx.x;   // < 12288
  const float* p = accP + (size_t)b * nchunk * 12288 + idx;
  float a = 0.f;
  for (int c = 0; c < nchunk; ++c) a += p[(size_t)c * 12288];
  out[b * 12288 + idx] = a;
}

// og[b,t,:] = bvo + sum_h (acc[b,h*24+t,:]/l) @ Wvo[h]
__global__ __launch_bounds__(128) void k_og(const float* __restrict__ accR,
    const float* __restrict__ lP, int nchunk,
    const float* __restrict__ Wvo, const float* __restrict__ bvo,
    float* __restrict__ og) {
  int row = blockIdx.x;  int b = row / 24, tq = row % 24;
  int e = threadIdx.x;
  __shared__ float invl[4];
  __shared__ float op[4 * 128];
  if (e < 4) {
    int hq = e * 24 + tq;
    float l = 0.f;
    const float* lp = lP + (size_t)b * nchunk * 96 + hq;
    for (int c = 0; c < nchunk; ++c) l += lp[(size_t)c * 96];
    invl[e] = 1.f / l;
  }
  __syncthreads();
  for (int h = 0; h < 4; ++h)
    op[h * 128 + e] = accR[(size_t)(b * 96 + h * 24 + tq) * 128 + e] * invl[h];
  __syncthreads();
  float acc = bvo[e];
  for (int h = 0; h < 4; ++h) {
    const float* w = Wvo + h * 16384;
    const float* o = op + h * 128;
    for (int j = 0; j < 128; ++j) acc += o[j] * w[j * 128 + e];
  }
  og[row * 128 + e] = acc;
}

// ---------------- output writers (lerp upsample) ----------------------------

__global__ __launch_bounds__(256) void k_gout(const float* __restrict__ og,
                                              float* __restrict__ out) {
  int b = blockIdx.y;
  const float* ogb = og + b * 24 * 128;
  float* ob = out + (size_t)b * 6291456;
  for (int i4 = blockIdx.x * 256 + threadIdx.x; i4 < 1572864; i4 += gridDim.x * 256) {
    int i = i4 * 4;
    int n = i >> 7, e = i & 127;
    float src = fmaxf((n + 0.5f) * (1.f / 2048.f) - 0.5f, 0.f);
    int t0 = (int)src; float lam = src - (float)t0; int t1 = min(t0 + 1, 23);
    float4 a = *(const float4*)&ogb[t0 * 128 + e];
    float4 c = *(const float4*)&ogb[t1 * 128 + e];
    float4 o;
    o.x = a.x + lam * (c.x - a.x); o.y = a.y + lam * (c.y - a.y);
    o.z = a.z + lam * (c.z - a.z); o.w = a.w + lam * (c.w - a.w);
    *(float4*)&ob[i] = o;
  }
}

// U[b,tau,o,p,q] = og_r[b,tau,:] @ up_w[:,o,p,q]
__global__ __launch_bounds__(256) void k_U(const float* __restrict__ og_r,
    const float* __restrict__ up_w, float* __restrict__ U) {
  int row = blockIdx.x;   // b*24+tau
  __shared__ float o[128];
  if (threadIdx.x < 128) o[threadIdx.x] = og_r[row * 128 + threadIdx.x];
  __syncthreads();
  for (int out0 = threadIdx.x; out0 < 8192; out0 += 256) {
    float a = 0.f;
    for (int c = 0; c < 128; ++c) a += o[c] * up_w[(size_t)c * 8192 + out0];
    U[(size_t)row * 8192 + out0] = a;
  }
}

__global__ __launch_bounds__(256) void k_up(const float* __restrict__ U,
    const float* __restrict__ up_b, float* __restrict__ out) {
  for (int i4 = blockIdx.x * 256 + threadIdx.x; i4 < 12582912; i4 += gridDim.x * 256) {
    int i = i4 * 4;
    int w0 = i & 63;
    int h  = (i >> 6) & 63;
    int o  = (i >> 12) & 127;
    int bt = i >> 19;                 // 0..95
    int b = bt / 24, tt = bt - b * 24;
    int ii = h >> 3, p = h & 7, j = w0 >> 3, q0 = w0 & 7;
    int n = tt * 64 + ii * 8 + j;
    float src = fmaxf((n + 0.5f) * (1.f / 64.f) - 0.5f, 0.f);
    int t0 = (int)src; float lam = src - (float)t0; int t1 = min(t0 + 1, 23);
    const float* u0 = U + (size_t)(b * 24 + t0) * 8192 + o * 64 + p * 8 + q0;
    const float* u1 = U + (size_t)(b * 24 + t1) * 8192 + o * 64 + p * 8 + q0;
    float bb = up_b[o];
    float4 a = *(const float4*)u0, c = *(const float4*)u1;
    float4 r;
    r.x = a.x + lam * (c.x - a.x) + bb; r.y = a.y + lam * (c.y - a.y) + bb;
    r.z = a.z + lam * (c.z - a.z) + bb; r.w = a.w + lam * (c.w - a.w) + bb;
    *(float4*)&out[i] = r;
  }
}

// ---------------------------------------------------------------------------

extern "C" void kernel_launch(void* const* d_in, const int* in_sizes, int n_in,
                              void* d_out, int out_size, void* d_ws, size_t ws_size,
                              hipStream_t stream) {
  (void)in_sizes; (void)n_in; (void)out_size; (void)ws_size;
  const float* gf    = (const float*)d_in[0];
  const float* gridf = (const float*)d_in[1];
  const float* gti   = (const float*)d_in[2];
  // d_in[3] grid_time_indices is unused by the reference
  const float* gek_w1 = (const float*)d_in[4],  *gek_b1 = (const float*)d_in[5];
  const float* gek_w2 = (const float*)d_in[6],  *gek_b2 = (const float*)d_in[7];
  const float* gev_w1 = (const float*)d_in[8],  *gev_b1 = (const float*)d_in[9];
  const float* gev_w2 = (const float*)d_in[10], *gev_b2 = (const float*)d_in[11];
  const float* rk_w1  = (const float*)d_in[12], *rk_b1  = (const float*)d_in[13];
  const float* rk_w2  = (const float*)d_in[14], *rk_b2  = (const float*)d_in[15];
  const float* rv_w1  = (const float*)d_in[16], *rv_b1  = (const float*)d_in[17];
  const float* rv_w2  = (const float*)d_in[18], *rv_b2  = (const float*)d_in[19];
  const float* te_w1  = (const float*)d_in[20], *te_b1  = (const float*)d_in[21];
  const float* te_w2  = (const float*)d_in[22], *te_b2  = (const float*)d_in[23];
  const float* pe_w   = (const float*)d_in[24], *pe_b   = (const float*)d_in[25];
  const float* up_w   = (const float*)d_in[26], *up_b   = (const float*)d_in[27];
  const float* ag_q_w = (const float*)d_in[28], *ag_q_b = (const float*)d_in[29];
  const float* ag_k_w = (const float*)d_in[30], *ag_k_b = (const float*)d_in[31];
  const float* ag_v_w = (const float*)d_in[32], *ag_v_b = (const float*)d_in[33];
  const float* ag_o_w = (const float*)d_in[34], *ag_o_b = (const float*)d_in[35];
  const float* ar_q_w = (const float*)d_in[36], *ar_q_b = (const float*)d_in[37];
  const float* ar_k_w = (const float*)d_in[38], *ar_k_b = (const float*)d_in[39];
  const float* ar_v_w = (const float*)d_in[40], *ar_v_b = (const float*)d_in[41];
  const float* ar_o_w = (const float*)d_in[42], *ar_o_b = (const float*)d_in[43];

  float* out = (float*)d_out;          // g_out (25165824 f) then up (50331648 f)
  float* ws = (float*)d_ws;
  size_t off = 0;
  auto A = [&](size_t n) { float* p = ws + off; off += n; return p; };
  float* te    = A(12288);
  float* q_g   = A(12288);   float* q_r   = A(12288);
  float* Wk_g  = A(16384);   float* bk_g  = A(128);
  float* Wv_g  = A(16384);   float* bv_g  = A(128);
  float* Wk_r  = A(16384);   float* bk_r  = A(128);
  float* Wv_r  = A(16384);   float* bv_r  = A(128);
  float* Wvo_g = A(65536);   float* bvo_g = A(128);
  float* Wvo_r = A(65536);   float* bvo_r = A(128);
  float* Pk_g  = A(49152);   float* ck_g  = A(384);
  float* Pk_r  = A(49152);   float* ck_r  = A(384);
  float* peT   = A(1048576);
  float* accP_g = A(3145728);  float* lP_g = A(24576);
  float* accP_r = A(1179648);  float* lP_r = A(9216);
  float* accG  = A(49152);   float* accR2 = A(49152);
  float* og_g  = A(12288);   float* og_r  = A(12288);
  float* patchP = A(3145728);
  float* patches = A(786432);
  float* U     = A(786432);
  // total ~10.6M floats (~42.3 MB)

  k_te<<<96, 128, 0, stream>>>(gti, te_w1, te_b1, te_w2, te_b2, te);
  k_q<<<dim3(96, 2), 128, 0, stream>>>(te, ag_q_w, ag_q_b, ar_q_w, ar_q_b, q_g, q_r);
  k_fold<<<dim3(129, 4), 128, 0, stream>>>(
      gek_w2, gek_b2, ag_k_w, ag_k_b, Wk_g, bk_g,
      gev_w2, gev_b2, ag_v_w, ag_v_b, Wv_g, bv_g,
      rk_w2,  rk_b2,  ar_k_w, ar_k_b, Wk_r, bk_r,
      rv_w2,  rv_b2,  ar_v_w, ar_v_b, Wv_r, bv_r);
  k_wvo<<<dim3(129, 8), 128, 0, stream>>>(
      Wv_g, bv_g, ag_o_w, ag_o_b, Wvo_g, bvo_g,
      Wv_r, bv_r, ar_o_w, ar_o_b, Wvo_r, bvo_r);
  k_pk<<<dim3(129, 8), 128, 0, stream>>>(
      Wk_g, bk_g, q_g, Pk_g, ck_g,
      Wk_r, bk_r, q_r, Pk_r, ck_r);
  k_transpose<<<dim3(256, 4), 256, 0, stream>>>(pe_w, peT);

  // graph branch: 49152 keys/batch, 64 chunks x 768 keys
  k_flash<64><<<dim3(64, 4), 256, 0, stream>>>(
      gf, gek_w1, gek_b1, gev_w1, gev_b1, Pk_g, ck_g, accP_g, lP_g, KLGc, 768);

  // grid branch: patch conv then 1536 keys/batch, 24 chunks x 64 keys
  k_patch<<<dim3(96, 4), 256, 0, stream>>>(gridf, peT, patchP);
  k_reduceK<<<3072, 256, 0, stream>>>(patchP, pe_b, patches, 786432, 4);
  k_flash<128><<<dim3(24, 4), 256, 0, stream>>>(
      patches, rk_w1, rk_b1, rv_w1, rv_b1, Pk_r, ck_r, accP_r, lP_r, KLRc, 64);

  k_reduceacc<<<dim3(48, 4), 256, 0, stream>>>(accP_g, accG, 64);
  k_reduceacc<<<dim3(48, 4), 256, 0, stream>>>(accP_r, accR2, 24);
  k_og<<<96, 128, 0, stream>>>(accG, lP_g, 64, Wvo_g, bvo_g, og_g);
  k_og<<<96, 128, 0, stream>>>(accR2, lP_r, 24, Wvo_r, bvo_r, og_r);

  k_gout<<<dim3(1024, 4), 256, 0, stream>>>(og_g, out);
  k_U<<<96, 256, 0, stream>>>(og_r, up_w, U);
  k_up<<<4096, 256, 0, stream>>>(U, up_b, out + 25165824);
}

// Round 2
// 542.638 us; speedup vs baseline: 2.6901x; 2.6901x over previous
//
#include <hip/hip_runtime.h>

// ---------------------------------------------------------------------------
// GraphGridCrossAttnModel — round 2: bf16 MFMA for flash-attn + patch conv.
// B=4 T=24 N=2048 DG=64 E=128 NH=4 HD=32 H=W=64 P=8 -> NP=64
// Identities (exact):
//  * k-path fold:  k = relu(x@w1+b1) @ (w2@kw) + (b2@kw+kb)
//  * s via Pk:     s[key,hq] = hidden_k . PkT[hq,:] + ck[hq]
//  * v-path fold:  o = (sum_i a_i * hidden_v_i) @ (Wv[:,hslice]@ow) + (bv@ow+ob)
//  * outputs are lerps of 24 rows: g_out = interp(og_g), up = interp(og_r@up_w)+b
// MFMA layout (16x16x32 bf16, m89-verified):
//  A: m=l&15, k=(l>>4)*8+j ; B: n=l&15, k=(l>>4)*8+j ; D: col=l&15, row=(l>>4)*4+reg
// ---------------------------------------------------------------------------

typedef unsigned short u16;
using bf8 = __attribute__((ext_vector_type(8))) short;
using f4v = __attribute__((ext_vector_type(4))) float;
#define MFMA16(a, b, c) __builtin_amdgcn_mfma_f32_16x16x32_bf16(a, b, c, 0, 0, 0)

constexpr float INV_SCALE = 0.17677669529663687f;   // 1/sqrt(32)

__device__ __forceinline__ u16 f2bf(float f) {
  unsigned u = __float_as_uint(f);
  u += 0x7FFFu + ((u >> 16) & 1u);
  return (u16)(u >> 16);
}
__device__ __forceinline__ unsigned pk2(float a, float b) {
  return (unsigned)f2bf(a) | ((unsigned)f2bf(b) << 16);
}

// ---------------- small precompute kernels ----------------------------------

__global__ __launch_bounds__(128) void k_te(const float* __restrict__ tidx,
    const float* __restrict__ w1, const float* __restrict__ b1,
    const float* __restrict__ w2, const float* __restrict__ b2,
    float* __restrict__ te) {
  int row = blockIdx.x, e = threadIdx.x;
  __shared__ float h[128];
  float tv = tidx[row];
  h[e] = fmaxf(tv * w1[e] + b1[e], 0.f);
  __syncthreads();
  float acc = b2[e];
  for (int j = 0; j < 128; ++j) acc += h[j] * w2[j * 128 + e];
  te[row * 128 + e] = acc;
}

__global__ __launch_bounds__(128) void k_q(const float* __restrict__ te,
    const float* __restrict__ wg, const float* __restrict__ bg,
    const float* __restrict__ wr, const float* __restrict__ br,
    float* __restrict__ qg, float* __restrict__ qr) {
  int row = blockIdx.x, e = threadIdx.x;
  const float* w = blockIdx.y ? wr : wg;
  const float* bb = blockIdx.y ? br : bg;
  float* out = blockIdx.y ? qr : qg;
  __shared__ float x[128];
  x[e] = te[row * 128 + e];
  __syncthreads();
  float acc = bb[e];
  for (int j = 0; j < 128; ++j) acc += x[j] * w[j * 128 + e];
  out[row * 128 + e] = acc;
}

// W = A@B (+ bias row j==128: Ob = Ab@B + Bb)
__global__ __launch_bounds__(128) void k_fold(
    const float* A0, const float* Ab0, const float* B0, const float* Bb0, float* O0, float* Ob0,
    const float* A1, const float* Ab1, const float* B1, const float* Bb1, float* O1, float* Ob1,
    const float* A2, const float* Ab2, const float* B2, const float* Bb2, float* O2, float* Ob2,
    const float* A3, const float* Ab3, const float* B3, const float* Bb3, float* O3, float* Ob3) {
  int task = blockIdx.y, j = blockIdx.x, e = threadIdx.x;
  const float *A, *Ab, *Bm, *Bb; float *O, *Ob;
  switch (task) {
    case 0: A=A0; Ab=Ab0; Bm=B0; Bb=Bb0; O=O0; Ob=Ob0; break;
    case 1: A=A1; Ab=Ab1; Bm=B1; Bb=Bb1; O=O1; Ob=Ob1; break;
    case 2: A=A2; Ab=Ab2; Bm=B2; Bb=Bb2; O=O2; Ob=Ob2; break;
    default:A=A3; Ab=Ab3; Bm=B3; Bb=Bb3; O=O3; Ob=Ob3; break;
  }
  __shared__ float a[128];
  a[e] = (j < 128) ? A[j * 128 + e] : Ab[e];
  __syncthreads();
  float acc = (j < 128) ? 0.f : Bb[e];
  for (int m = 0; m < 128; ++m) acc += a[m] * Bm[m * 128 + e];
  if (j < 128) O[j * 128 + e] = acc; else Ob[e] = acc;
}

// Wvo[h][j][e] = sum_d Wv[j][h*32+d]*ow[(h*32+d)*128+e]; bvo = bv@ow + ob
__global__ __launch_bounds__(128) void k_wvo(
    const float* Wv_g, const float* bv_g, const float* ow_g, const float* ob_g, float* Wvo_g, float* bvo_g,
    const float* Wv_r, const float* bv_r, const float* ow_r, const float* ob_r, float* Wvo_r, float* bvo_r) {
  int j = blockIdx.x, e = threadIdx.x;
  int br = blockIdx.y >> 2, h = blockIdx.y & 3;
  const float* Wv = br ? Wv_r : Wv_g;  const float* bv = br ? bv_r : bv_g;
  const float* ow = br ? ow_r : ow_g;  const float* ob = br ? ob_r : ob_g;
  float* Wvo = br ? Wvo_r : Wvo_g;     float* bvo = br ? bvo_r : bvo_g;
  if (j < 128) {
    __shared__ float wrow[32];
    if (e < 32) wrow[e] = Wv[j * 128 + h * 32 + e];
    __syncthreads();
    float acc = 0.f;
    for (int d = 0; d < 32; ++d) acc += wrow[d] * ow[(h * 32 + d) * 128 + e];
    Wvo[(h * 128 + j) * 128 + e] = acc;
  } else if (h == 0) {
    __shared__ float bbv[128];
    bbv[e] = bv[e];
    __syncthreads();
    float acc = ob[e];
    for (int m = 0; m < 128; ++m) acc += bbv[m] * ow[m * 128 + e];
    bvo[e] = acc;
  }
}

// PkT[b][hq][j] (bf16, pitch 136) = INV_SCALE * sum_d Wk[j][h*32+d]*q[b,t][h*32+d]
// j==128 -> ck[b][hq] (fp32)
__global__ __launch_bounds__(128) void k_pk(
    const float* Wk_g, const float* bk_g, const float* q_g, u16* PkT_g, float* ck_g,
    const float* Wk_r, const float* bk_r, const float* q_r, u16* PkT_r, float* ck_r) {
  int j = blockIdx.x;
  int br = blockIdx.y >> 2, b = blockIdx.y & 3;
  int hq = threadIdx.x;
  if (hq >= 96) return;
  const float* Wk = br ? Wk_r : Wk_g;  const float* bk = br ? bk_r : bk_g;
  const float* q  = br ? q_r  : q_g;
  u16* PkT = br ? PkT_r : PkT_g;       float* ck = br ? ck_r : ck_g;
  int h = hq / 24, t = hq % 24;
  const float* qrow = q + (b * 24 + t) * 128 + h * 32;
  if (j < 128) {
    const float* wrow = Wk + j * 128 + h * 32;
    float acc = 0.f;
    for (int d = 0; d < 32; ++d) acc += wrow[d] * qrow[d];
    PkT[((size_t)b * 96 + hq) * 136 + j] = f2bf(acc * INV_SCALE);
  } else {
    float acc = 0.f;
    for (int d = 0; d < 32; ++d) acc += bk[h * 32 + d] * qrow[d];
    ck[b * 96 + hq] = acc * INV_SCALE;
  }
}

// W1c[c][din] bf16 : c<128 -> w1k col c ; c>=128 -> w1v col c-128
__global__ __launch_bounds__(128) void k_w1c(
    const float* gk_w1, const float* gv_w1, const float* rk_w1, const float* rv_w1,
    u16* W1c_g, u16* W1c_r) {
  int c = blockIdx.x, br = blockIdx.y, d = threadIdx.x;
  int DIN = br ? 128 : 64;
  if (d >= DIN) return;
  const float* src = br ? (c < 128 ? rk_w1 : rv_w1) : (c < 128 ? gk_w1 : gv_w1);
  u16* dst = br ? W1c_r : W1c_g;
  dst[c * DIN + d] = f2bf(src[d * 128 + (c & 127)]);
}

// peB = bf16(pe_w)  (128 x 8192, same layout)
__global__ __launch_bounds__(256) void k_cvt(const float* __restrict__ src,
                                             u16* __restrict__ dst) {
  int i = (blockIdx.x * 256 + threadIdx.x) * 4;
  float4 v = *(const float4*)(src + i);
  uint2 o; o.x = pk2(v.x, v.y); o.y = pk2(v.z, v.w);
  *(uint2*)&dst[i] = o;
}

// ---------------- fused flash attention, bf16 MFMA ---------------------------
// Per block: batch b, key-chunk. 4 waves. Tiles of 64 keys.
// Hk LDS [key][136] ; HvT LDS [hid][72] (time-shared buffer) ; Pt [hq][72].

template <int DIN>
__global__ __launch_bounds__(256) void k_flash(
    const float* __restrict__ X,
    const u16* __restrict__ W1c,            // [256][DIN] bf16 (k cols | v cols)
    const float* __restrict__ b1k, const float* __restrict__ b1v,
    const u16* __restrict__ PkT,            // [b][96][136] bf16
    const float* __restrict__ ck,           // [b][96]
    float* __restrict__ accP, float* __restrict__ lP,
    int KL, int kpb) {
  constexpr int KS = DIN / 32;
  constexpr int PD = DIN + 8;
  constexpr int PH = 136, PV = 72, PP = 72;
  int b = blockIdx.y, chunk = blockIdx.x, nchunk = gridDim.x;
  int t = threadIdx.x;
  int l = t & 63, w = t >> 6;
  int l16 = l & 15, l4 = l >> 4;

  __shared__ __align__(16) u16 Xt[64 * PD];
  __shared__ __align__(16) u16 HB[9216];        // Hk[64][136] / HvT[128][72]
  __shared__ __align__(16) u16 Pt[96 * PP];
  __shared__ __align__(16) u16 Pk_s[96 * 136];
  __shared__ float lred[384];

  const float* Xb = X + (size_t)b * KL * DIN + (size_t)chunk * kpb * DIN;

  // stage PkT[b] into LDS (once per block)
  {
    const unsigned* ps = (const unsigned*)(PkT + (size_t)b * 96 * 136);
    unsigned* pd = (unsigned*)Pk_s;
    for (int i = t; i < 96 * 136 / 2; i += 256) pd[i] = ps[i];
  }

  // persistent register fragments: W1 (A for G1a / B for G1b), biases, ck
  bf8 wkA[2][KS], wvB[2][KS];
#pragma unroll
  for (int m = 0; m < 2; ++m)
#pragma unroll
    for (int ks = 0; ks < KS; ++ks) {
      int hid = w * 32 + m * 16 + l16;
      wkA[m][ks] = *(const bf8*)(W1c + (size_t)hid * DIN + ks * 32 + l4 * 8);
      wvB[m][ks] = *(const bf8*)(W1c + (size_t)(128 + hid) * DIN + ks * 32 + l4 * 8);
    }
  float bkA[2][4], bvB[2], ckr[6];
#pragma unroll
  for (int m = 0; m < 2; ++m)
#pragma unroll
    for (int r = 0; r < 4; ++r) bkA[m][r] = b1k[w * 32 + m * 16 + l4 * 4 + r];
#pragma unroll
  for (int n = 0; n < 2; ++n) bvB[n] = b1v[w * 32 + n * 16 + l16];
#pragma unroll
  for (int n = 0; n < 6; ++n) ckr[n] = ck[b * 96 + n * 16 + l16];

  f4v accO[6][2];
#pragma unroll
  for (int m = 0; m < 6; ++m)
#pragma unroll
    for (int n = 0; n < 2; ++n) accO[m][n] = (f4v){0.f, 0.f, 0.f, 0.f};
  float lacc[6] = {0.f, 0.f, 0.f, 0.f, 0.f, 0.f};

  int ntile = kpb >> 6;
  for (int kt = 0; kt < ntile; ++kt) {
    // ---- stage X tile (64 keys x DIN), fp32 -> bf16 ----
    const float* Xrow = Xb + (size_t)kt * 64 * DIN;
#pragma unroll
    for (int r = 0; r < DIN / 16; ++r) {
      int idx = (r * 256 + t) * 4;
      int key = idx / DIN, din = idx % DIN;
      float4 v = *(const float4*)(Xrow + idx);
      uint2 o; o.x = pk2(v.x, v.y); o.y = pk2(v.z, v.w);
      *(uint2*)&Xt[key * PD + din] = o;
    }
    __syncthreads();                                   // b1

    // ---- G1a: Hk = W1k^T @ X^T  (M=hid 32/wave, N=64 keys) ----
    {
      f4v hk[2][4];
#pragma unroll
      for (int m = 0; m < 2; ++m)
#pragma unroll
        for (int n = 0; n < 4; ++n) hk[m][n] = (f4v){0.f, 0.f, 0.f, 0.f};
#pragma unroll
      for (int ks = 0; ks < KS; ++ks) {
        bf8 xf[4];
#pragma unroll
        for (int n = 0; n < 4; ++n)
          xf[n] = *(const bf8*)&Xt[(n * 16 + l16) * PD + ks * 32 + l4 * 8];
#pragma unroll
        for (int m = 0; m < 2; ++m)
#pragma unroll
          for (int n = 0; n < 4; ++n) hk[m][n] = MFMA16(wkA[m][ks], xf[n], hk[m][n]);
      }
#pragma unroll
      for (int m = 0; m < 2; ++m)
#pragma unroll
        for (int n = 0; n < 4; ++n) {
          int key = n * 16 + l16;
          int hid0 = w * 32 + m * 16 + l4 * 4;
          float v0 = fmaxf(hk[m][n][0] + bkA[m][0], 0.f);
          float v1 = fmaxf(hk[m][n][1] + bkA[m][1], 0.f);
          float v2 = fmaxf(hk[m][n][2] + bkA[m][2], 0.f);
          float v3 = fmaxf(hk[m][n][3] + bkA[m][3], 0.f);
          uint2 o; o.x = pk2(v0, v1); o.y = pk2(v2, v3);
          *(uint2*)&HB[key * PH + hid0] = o;
        }
    }
    __syncthreads();                                   // b2

    // ---- G2: S = Hk @ Pk (wave's 16 keys x 96 hq, K=128) ----
    {
      f4v sa[6];
#pragma unroll
      for (int n = 0; n < 6; ++n) sa[n] = (f4v){ckr[n], ckr[n], ckr[n], ckr[n]};
#pragma unroll
      for (int ks = 0; ks < 4; ++ks) {
        bf8 a = *(const bf8*)&HB[(w * 16 + l16) * PH + ks * 32 + l4 * 8];
#pragma unroll
        for (int n = 0; n < 6; ++n) {
          bf8 bp = *(const bf8*)&Pk_s[(n * 16 + l16) * 136 + ks * 32 + l4 * 8];
          sa[n] = MFMA16(a, bp, sa[n]);
        }
      }
#pragma unroll
      for (int n = 0; n < 6; ++n) {
        float e0 = __expf(sa[n][0]), e1 = __expf(sa[n][1]);
        float e2 = __expf(sa[n][2]), e3 = __expf(sa[n][3]);
        float ls = (e0 + e1) + (e2 + e3);
        ls += __shfl_xor(ls, 16);
        ls += __shfl_xor(ls, 32);
        lacc[n] += ls;
        uint2 o; o.x = pk2(e0, e1); o.y = pk2(e2, e3);
        *(uint2*)&Pt[(n * 16 + l16) * PP + w * 16 + l4 * 4] = o;
      }
    }
    __syncthreads();                                   // b3 (Hk dead, Pt ready)

    // ---- G1b: Hv = X @ W1v (M=64 keys, N=hid 32/wave) -> HvT[hid][key] ----
    {
      f4v hv[4][2];
#pragma unroll
      for (int m = 0; m < 4; ++m)
#pragma unroll
        for (int n = 0; n < 2; ++n) hv[m][n] = (f4v){0.f, 0.f, 0.f, 0.f};
#pragma unroll
      for (int ks = 0; ks < KS; ++ks) {
        bf8 xa[4];
#pragma unroll
        for (int m = 0; m < 4; ++m)
          xa[m] = *(const bf8*)&Xt[(m * 16 + l16) * PD + ks * 32 + l4 * 8];
#pragma unroll
        for (int m = 0; m < 4; ++m)
#pragma unroll
          for (int n = 0; n < 2; ++n) hv[m][n] = MFMA16(xa[m], wvB[n][ks], hv[m][n]);
      }
#pragma unroll
      for (int m = 0; m < 4; ++m)
#pragma unroll
        for (int n = 0; n < 2; ++n) {
          int d = w * 32 + n * 16 + l16;
          int key0 = m * 16 + l4 * 4;
          float v0 = fmaxf(hv[m][n][0] + bvB[n], 0.f);
          float v1 = fmaxf(hv[m][n][1] + bvB[n], 0.f);
          float v2 = fmaxf(hv[m][n][2] + bvB[n], 0.f);
          float v3 = fmaxf(hv[m][n][3] + bvB[n], 0.f);
          uint2 o; o.x = pk2(v0, v1); o.y = pk2(v2, v3);
          *(uint2*)&HB[d * PV + key0] = o;
        }
    }
    __syncthreads();                                   // b4 (HvT ready)

    // ---- G3: ACC += P^T @ Hv  (M=96 hq, N=d 32/wave, K=64 keys) ----
#pragma unroll
    for (int ks = 0; ks < 2; ++ks) {
      bf8 pa[6];
#pragma unroll
      for (int m = 0; m < 6; ++m)
        pa[m] = *(const bf8*)&Pt[(m * 16 + l16) * PP + ks * 32 + l4 * 8];
#pragma unroll
      for (int n = 0; n < 2; ++n) {
        bf8 hb = *(const bf8*)&HB[(w * 32 + n * 16 + l16) * PV + ks * 32 + l4 * 8];
#pragma unroll
        for (int m = 0; m < 6; ++m) accO[m][n] = MFMA16(pa[m], hb, accO[m][n]);
      }
    }
    __syncthreads();                                   // protect Xt/Pt for next tile
  }

  // ---- write partial ACC (96x128 fp32) and partial l (96) ----
  float* ap = accP + (size_t)(b * nchunk + chunk) * 96 * 128;
#pragma unroll
  for (int m = 0; m < 6; ++m)
#pragma unroll
    for (int n = 0; n < 2; ++n) {
      int d = w * 32 + n * 16 + l16;
#pragma unroll
      for (int r = 0; r < 4; ++r) {
        int hq = m * 16 + l4 * 4 + r;
        ap[hq * 128 + d] = accO[m][n][r];
      }
    }
  if (l4 == 0) {
#pragma unroll
    for (int n = 0; n < 6; ++n) lred[w * 96 + n * 16 + l16] = lacc[n];
  }
  __syncthreads();
  if (t < 96) {
    float s = lred[t] + lred[96 + t] + lred[192 + t] + lred[288 + t];
    lP[(size_t)(b * nchunk + chunk) * 96 + t] = s;
  }
}

// ---------------- patch conv, bf16 MFMA (implicit GEMM, split-K) -------------

__global__ __launch_bounds__(256) void k_patch(const float* __restrict__ X,
    const u16* __restrict__ peB, float* __restrict__ patchP) {
  int bt = blockIdx.x;      // 0..95
  int kc = blockIdx.y;      // 0..3 : chunk of 32 channels
  int t = threadIdx.x;
  int l = t & 63, w = t >> 6;
  int l16 = l & 15, l4 = l >> 4;
  const float* Xbt = X + (size_t)bt * 524288;

  __shared__ __align__(16) u16 Xp[64 * 72];
  __shared__ __align__(16) u16 Wt[128 * 72];

  f4v acc[4][2];
#pragma unroll
  for (int m = 0; m < 4; ++m)
#pragma unroll
    for (int n = 0; n < 2; ++n) acc[m][n] = (f4v){0.f, 0.f, 0.f, 0.f};

  for (int ks = 0; ks < 32; ++ks) {
    int c = kc * 32 + ks;
    const float* img = Xbt + (size_t)c * 4096;
#pragma unroll
    for (int r = 0; r < 4; ++r) {          // X tile: one 64x64 channel image
      int idx = (r * 256 + t) * 4;
      int h = idx >> 6, w0 = idx & 63;
      float4 v = *(const float4*)(img + idx);
      int patch = (h >> 3) * 8 + (w0 >> 3);
      int within = (h & 7) * 8 + (w0 & 7);
      uint2 o; o.x = pk2(v.x, v.y); o.y = pk2(v.z, v.w);
      *(uint2*)&Xp[patch * 72 + within] = o;
    }
#pragma unroll
    for (int r = 0; r < 4; ++r) {          // W tile: 128 c_out x 64 k
      int idx = r * 256 + t;               // uint4 index
      int co = idx >> 3, kq = idx & 7;
      uint4 v = *(const uint4*)(peB + (size_t)co * 8192 + c * 64 + kq * 8);
      *(uint4*)&Wt[co * 72 + kq * 8] = v;
    }
    __syncthreads();
#pragma unroll
    for (int ks2 = 0; ks2 < 2; ++ks2) {
      bf8 af[4];
#pragma unroll
      for (int m = 0; m < 4; ++m)
        af[m] = *(const bf8*)&Xp[(m * 16 + l16) * 72 + ks2 * 32 + l4 * 8];
#pragma unroll
      for (int n = 0; n < 2; ++n) {
        bf8 bf_ = *(const bf8*)&Wt[(w * 32 + n * 16 + l16) * 72 + ks2 * 32 + l4 * 8];
#pragma unroll
        for (int m = 0; m < 4; ++m) acc[m][n] = MFMA16(af[m], bf_, acc[m][n]);
      }
    }
    __syncthreads();
  }
  float* outp = patchP + ((size_t)kc * 6144 + bt * 64) * 128;
#pragma unroll
  for (int m = 0; m < 4; ++m)
#pragma unroll
    for (int n = 0; n < 2; ++n) {
      int d = w * 32 + n * 16 + l16;
#pragma unroll
      for (int r = 0; r < 4; ++r) {
        int patch = m * 16 + l4 * 4 + r;
        outp[patch * 128 + d] = acc[m][n][r];
      }
    }
}

__global__ __launch_bounds__(256) void k_reduceK(const float* __restrict__ P,
    const float* __restrict__ bias, float* __restrict__ out, int n, int nc) {
  int idx = blockIdx.x * 256 + threadIdx.x;
  if (idx >= n) return;
  float a = bias[idx & 127];
  for (int c = 0; c < nc; ++c) a += P[(size_t)c * n + idx];
  out[idx] = a;
}

__global__ __launch_bounds__(256) void k_reduceacc(const float* __restrict__ accP,
    float* __restrict__ out, int nchunk) {
  int b = blockIdx.y;
  int idx = blockIdx.x * 256 + threadIdx.x;   // < 12288
  const float* p = accP + (size_t)b * nchunk * 12288 + idx;
  float a = 0.f;
  for (int c = 0; c < nchunk; ++c) a += p[(size_t)c * 12288];
  out[b * 12288 + idx] = a;
}

// og[b,t,:] = bvo + sum_h (acc[b,h*24+t,:]/l) @ Wvo[h]
__global__ __launch_bounds__(128) void k_og(const float* __restrict__ accR,
    const float* __restrict__ lP, int nchunk,
    const float* __restrict__ Wvo, const float* __restrict__ bvo,
    float* __restrict__ og) {
  int row = blockIdx.x;  int b = row / 24, tq = row % 24;
  int e = threadIdx.x;
  __shared__ float invl[4];
  __shared__ float op[4 * 128];
  if (e < 4) {
    int hq = e * 24 + tq;
    float lsum = 0.f;
    const float* lp = lP + (size_t)b * nchunk * 96 + hq;
    for (int c = 0; c < nchunk; ++c) lsum += lp[(size_t)c * 96];
    invl[e] = 1.f / lsum;
  }
  __syncthreads();
  for (int h = 0; h < 4; ++h)
    op[h * 128 + e] = accR[(size_t)(b * 96 + h * 24 + tq) * 128 + e] * invl[h];
  __syncthreads();
  float acc = bvo[e];
  for (int h = 0; h < 4; ++h) {
    const float* ww = Wvo + h * 16384;
    const float* o = op + h * 128;
    for (int j = 0; j < 128; ++j) acc += o[j] * ww[j * 128 + e];
  }
  og[row * 128 + e] = acc;
}

// ---------------- output writers (lerp upsample) ----------------------------

__global__ __launch_bounds__(256) void k_gout(const float* __restrict__ og,
                                              float* __restrict__ out) {
  int b = blockIdx.y;
  const float* ogb = og + b * 24 * 128;
  float* ob = out + (size_t)b * 6291456;
  for (int i4 = blockIdx.x * 256 + threadIdx.x; i4 < 1572864; i4 += gridDim.x * 256) {
    int i = i4 * 4;
    int n = i >> 7, e = i & 127;
    float src = fmaxf((n + 0.5f) * (1.f / 2048.f) - 0.5f, 0.f);
    int t0 = (int)src; float lam = src - (float)t0; int t1 = min(t0 + 1, 23);
    float4 a = *(const float4*)&ogb[t0 * 128 + e];
    float4 c = *(const float4*)&ogb[t1 * 128 + e];
    float4 o;
    o.x = a.x + lam * (c.x - a.x); o.y = a.y + lam * (c.y - a.y);
    o.z = a.z + lam * (c.z - a.z); o.w = a.w + lam * (c.w - a.w);
    *(float4*)&ob[i] = o;
  }
}

// U[b,tau,o,p,q] = og_r[b,tau,:] @ up_w[:,o,p,q]
__global__ __launch_bounds__(256) void k_U(const float* __restrict__ og_r,
    const float* __restrict__ up_w, float* __restrict__ U) {
  int row = blockIdx.x;   // b*24+tau
  __shared__ float o[128];
  if (threadIdx.x < 128) o[threadIdx.x] = og_r[row * 128 + threadIdx.x];
  __syncthreads();
  for (int out0 = threadIdx.x; out0 < 8192; out0 += 256) {
    float a = 0.f;
    for (int c = 0; c < 128; ++c) a += o[c] * up_w[(size_t)c * 8192 + out0];
    U[(size_t)row * 8192 + out0] = a;
  }
}

__global__ __launch_bounds__(256) void k_up(const float* __restrict__ U,
    const float* __restrict__ up_b, float* __restrict__ out) {
  for (int i4 = blockIdx.x * 256 + threadIdx.x; i4 < 12582912; i4 += gridDim.x * 256) {
    int i = i4 * 4;
    int w0 = i & 63;
    int h  = (i >> 6) & 63;
    int o  = (i >> 12) & 127;
    int bt = i >> 19;                 // 0..95
    int b = bt / 24, tt = bt - b * 24;
    int ii = h >> 3, p = h & 7, j = w0 >> 3, q0 = w0 & 7;
    int n = tt * 64 + ii * 8 + j;
    float src = fmaxf((n + 0.5f) * (1.f / 64.f) - 0.5f, 0.f);
    int t0 = (int)src; float lam = src - (float)t0; int t1 = min(t0 + 1, 23);
    const float* u0 = U + (size_t)(b * 24 + t0) * 8192 + o * 64 + p * 8 + q0;
    const float* u1 = U + (size_t)(b * 24 + t1) * 8192 + o * 64 + p * 8 + q0;
    float bb = up_b[o];
    float4 a = *(const float4*)u0, c = *(const float4*)u1;
    float4 r;
    r.x = a.x + lam * (c.x - a.x) + bb; r.y = a.y + lam * (c.y - a.y) + bb;
    r.z = a.z + lam * (c.z - a.z) + bb; r.w = a.w + lam * (c.w - a.w) + bb;
    *(float4*)&out[i] = r;
  }
}

// ---------------------------------------------------------------------------

extern "C" void kernel_launch(void* const* d_in, const int* in_sizes, int n_in,
                              void* d_out, int out_size, void* d_ws, size_t ws_size,
                              hipStream_t stream) {
  (void)in_sizes; (void)n_in; (void)out_size; (void)ws_size;
  const float* gf    = (const float*)d_in[0];
  const float* gridf = (const float*)d_in[1];
  const float* gti   = (const float*)d_in[2];
  const float* gek_w1 = (const float*)d_in[4],  *gek_b1 = (const float*)d_in[5];
  const float* gek_w2 = (const float*)d_in[6],  *gek_b2 = (const float*)d_in[7];
  const float* gev_w1 = (const float*)d_in[8],  *gev_b1 = (const float*)d_in[9];
  const float* gev_w2 = (const float*)d_in[10], *gev_b2 = (const float*)d_in[11];
  const float* rk_w1  = (const float*)d_in[12], *rk_b1  = (const float*)d_in[13];
  const float* rk_w2  = (const float*)d_in[14], *rk_b2  = (const float*)d_in[15];
  const float* rv_w1  = (const float*)d_in[16], *rv_b1  = (const float*)d_in[17];
  const float* rv_w2  = (const float*)d_in[18], *rv_b2  = (const float*)d_in[19];
  const float* te_w1  = (const float*)d_in[20], *te_b1  = (const float*)d_in[21];
  const float* te_w2  = (const float*)d_in[22], *te_b2  = (const float*)d_in[23];
  const float* pe_w   = (const float*)d_in[24], *pe_b   = (const float*)d_in[25];
  const float* up_w   = (const float*)d_in[26], *up_b   = (const float*)d_in[27];
  const float* ag_q_w = (const float*)d_in[28], *ag_q_b = (const float*)d_in[29];
  const float* ag_k_w = (const float*)d_in[30], *ag_k_b = (const float*)d_in[31];
  const float* ag_v_w = (const float*)d_in[32], *ag_v_b = (const float*)d_in[33];
  const float* ag_o_w = (const float*)d_in[34], *ag_o_b = (const float*)d_in[35];
  const float* ar_q_w = (const float*)d_in[36], *ar_q_b = (const float*)d_in[37];
  const float* ar_k_w = (const float*)d_in[38], *ar_k_b = (const float*)d_in[39];
  const float* ar_v_w = (const float*)d_in[40], *ar_v_b = (const float*)d_in[41];
  const float* ar_o_w = (const float*)d_in[42], *ar_o_b = (const float*)d_in[43];

  float* out = (float*)d_out;          // g_out (25165824 f) then up (50331648 f)
  float* ws = (float*)d_ws;
  size_t off = 0;
  auto A = [&](size_t n) { float* p = ws + off; off += n; return p; };
  float* te    = A(12288);
  float* q_g   = A(12288);   float* q_r   = A(12288);
  float* Wk_g  = A(16384);   float* bk_g  = A(128);
  float* Wv_g  = A(16384);   float* bv_g  = A(128);
  float* Wk_r  = A(16384);   float* bk_r  = A(128);
  float* Wv_r  = A(16384);   float* bv_r  = A(128);
  float* Wvo_g = A(65536);   float* bvo_g = A(128);
  float* Wvo_r = A(65536);   float* bvo_r = A(128);
  float* ck_g  = A(384);     float* ck_r  = A(384);
  u16*   PkT_g = (u16*)A(26112);   // 96*136*4b bf16
  u16*   PkT_r = (u16*)A(26112);
  u16*   W1c_g = (u16*)A(8192);    // 256*64 bf16
  u16*   W1c_r = (u16*)A(16384);   // 256*128 bf16
  u16*   peB   = (u16*)A(524288);  // 128*8192 bf16
  float* lP_g  = A(49152);   float* lP_r  = A(9216);
  float* accG  = A(49152);   float* accR2 = A(49152);
  float* og_g  = A(12288);   float* og_r  = A(12288);
  float* patches = A(786432);
  float* BIG   = A(6291456);       // accP_g -> patchP -> accP_r -> U (stream-serial reuse)
  float* accP_g = BIG;             // 4*128*12288
  float* patchP = BIG;             // 4*6144*128 = 3145728
  float* accP_r = BIG;             // 4*24*12288 = 1179648
  float* U      = BIG;             // 96*8192 = 786432
  // total ~8.0M floats (~32 MB)

  k_te<<<96, 128, 0, stream>>>(gti, te_w1, te_b1, te_w2, te_b2, te);
  k_q<<<dim3(96, 2), 128, 0, stream>>>(te, ag_q_w, ag_q_b, ar_q_w, ar_q_b, q_g, q_r);
  k_fold<<<dim3(129, 4), 128, 0, stream>>>(
      gek_w2, gek_b2, ag_k_w, ag_k_b, Wk_g, bk_g,
      gev_w2, gev_b2, ag_v_w, ag_v_b, Wv_g, bv_g,
      rk_w2,  rk_b2,  ar_k_w, ar_k_b, Wk_r, bk_r,
      rv_w2,  rv_b2,  ar_v_w, ar_v_b, Wv_r, bv_r);
  k_wvo<<<dim3(129, 8), 128, 0, stream>>>(
      Wv_g, bv_g, ag_o_w, ag_o_b, Wvo_g, bvo_g,
      Wv_r, bv_r, ar_o_w, ar_o_b, Wvo_r, bvo_r);
  k_pk<<<dim3(129, 8), 128, 0, stream>>>(
      Wk_g, bk_g, q_g, PkT_g, ck_g,
      Wk_r, bk_r, q_r, PkT_r, ck_r);
  k_w1c<<<dim3(256, 2), 128, 0, stream>>>(gek_w1, gev_w1, rk_w1, rv_w1, W1c_g, W1c_r);
  k_cvt<<<1024, 256, 0, stream>>>(pe_w, peB);

  // graph branch: 49152 keys/batch, 128 chunks x 384 keys (6 tiles of 64)
  k_flash<64><<<dim3(128, 4), 256, 0, stream>>>(
      gf, W1c_g, gek_b1, gev_b1, PkT_g, ck_g, accP_g, lP_g, 49152, 384);
  k_reduceacc<<<dim3(48, 4), 256, 0, stream>>>(accP_g, accG, 128);
  k_og<<<96, 128, 0, stream>>>(accG, lP_g, 128, Wvo_g, bvo_g, og_g);
  k_gout<<<dim3(1024, 4), 256, 0, stream>>>(og_g, out);

  // grid branch: patch conv (MFMA, split-K 4) then 1536 keys/batch
  k_patch<<<dim3(96, 4), 256, 0, stream>>>(gridf, peB, patchP);
  k_reduceK<<<3072, 256, 0, stream>>>(patchP, pe_b, patches, 786432, 4);
  k_flash<128><<<dim3(24, 4), 256, 0, stream>>>(
      patches, W1c_r, rk_b1, rv_b1, PkT_r, ck_r, accP_r, lP_r, 1536, 64);
  k_reduceacc<<<dim3(48, 4), 256, 0, stream>>>(accP_r, accR2, 24);
  k_og<<<96, 128, 0, stream>>>(accR2, lP_r, 24, Wvo_r, bvo_r, og_r);
  k_U<<<96, 256, 0, stream>>>(og_r, up_w, U);
  k_up<<<4096, 256, 0, stream>>>(U, up_b, out + 25165824);
}

// Round 3
// 376.127 us; speedup vs baseline: 3.8810x; 1.4427x over previous
//
#include <hip/hip_runtime.h>

// ---------------------------------------------------------------------------
// GraphGridCrossAttnModel — round 3: pipeline/occupancy pass.
// B=4 T=24 N=2048 DG=64 E=128 NH=4 HD=32 H=W=64 P=8 -> NP=64
// Changes vs r2: k_U reads up_w once; k_patch split-K8 + swizzled Wt + reg
// prefetch (2 barriers/128-K-step); k_flash Xt double-buffer + reg prefetch
// (4 barriers/tile); flash<128> consumes patch partials directly (k_reduceK
// gone); k_te+k_q fused; k_wvo+k_pk fused.
// MFMA layout (16x16x32 bf16, m89-verified):
//  A: m=l&15, k=(l>>4)*8+j ; B: n=l&15, k=(l>>4)*8+j ; D: col=l&15, row=(l>>4)*4+reg
// ---------------------------------------------------------------------------

typedef unsigned short u16;
using bf8 = __attribute__((ext_vector_type(8))) short;
using f4v = __attribute__((ext_vector_type(4))) float;
#define MFMA16(a, b, c) __builtin_amdgcn_mfma_f32_16x16x32_bf16(a, b, c, 0, 0, 0)

constexpr float INV_SCALE = 0.17677669529663687f;   // 1/sqrt(32)

__device__ __forceinline__ u16 f2bf(float f) {
  unsigned u = __float_as_uint(f);
  u += 0x7FFFu + ((u >> 16) & 1u);
  return (u16)(u >> 16);
}
__device__ __forceinline__ unsigned pk2(float a, float b) {
  return (unsigned)f2bf(a) | ((unsigned)f2bf(b) << 16);
}

// ---------------- small precompute kernels ----------------------------------

// te (in LDS only) -> q_g, q_r
__global__ __launch_bounds__(128) void k_teq(const float* __restrict__ tidx,
    const float* __restrict__ w1, const float* __restrict__ b1,
    const float* __restrict__ w2, const float* __restrict__ b2,
    const float* __restrict__ wg, const float* __restrict__ bg,
    const float* __restrict__ wr, const float* __restrict__ br,
    float* __restrict__ qg, float* __restrict__ qr) {
  int row = blockIdx.x, e = threadIdx.x;
  __shared__ float h[128];
  __shared__ float te_s[128];
  float tv = tidx[row];
  h[e] = fmaxf(tv * w1[e] + b1[e], 0.f);
  __syncthreads();
  float a = b2[e];
  for (int j = 0; j < 128; ++j) a += h[j] * w2[j * 128 + e];
  te_s[e] = a;
  __syncthreads();
  float ag = bg[e], ar = br[e];
  for (int j = 0; j < 128; ++j) {
    float x = te_s[j];
    ag += x * wg[j * 128 + e];
    ar += x * wr[j * 128 + e];
  }
  qg[row * 128 + e] = ag;
  qr[row * 128 + e] = ar;
}

// W = A@B (+ bias row j==128: Ob = Ab@B + Bb)
__global__ __launch_bounds__(128) void k_fold(
    const float* A0, const float* Ab0, const float* B0, const float* Bb0, float* O0, float* Ob0,
    const float* A1, const float* Ab1, const float* B1, const float* Bb1, float* O1, float* Ob1,
    const float* A2, const float* Ab2, const float* B2, const float* Bb2, float* O2, float* Ob2,
    const float* A3, const float* Ab3, const float* B3, const float* Bb3, float* O3, float* Ob3) {
  int task = blockIdx.y, j = blockIdx.x, e = threadIdx.x;
  const float *A, *Ab, *Bm, *Bb; float *O, *Ob;
  switch (task) {
    case 0: A=A0; Ab=Ab0; Bm=B0; Bb=Bb0; O=O0; Ob=Ob0; break;
    case 1: A=A1; Ab=Ab1; Bm=B1; Bb=Bb1; O=O1; Ob=Ob1; break;
    case 2: A=A2; Ab=Ab2; Bm=B2; Bb=Bb2; O=O2; Ob=Ob2; break;
    default:A=A3; Ab=Ab3; Bm=B3; Bb=Bb3; O=O3; Ob=Ob3; break;
  }
  __shared__ float a[128];
  a[e] = (j < 128) ? A[j * 128 + e] : Ab[e];
  __syncthreads();
  float acc = (j < 128) ? 0.f : Bb[e];
  for (int m = 0; m < 128; ++m) acc += a[m] * Bm[m * 128 + e];
  if (j < 128) O[j * 128 + e] = acc; else Ob[e] = acc;
}

// merged: y<8 -> Wvo/bvo tasks ; y>=8 -> PkT/ck tasks
__global__ __launch_bounds__(128) void k_wvopk(
    const float* Wv_g, const float* bv_g, const float* ow_g, const float* ob_g, float* Wvo_g, float* bvo_g,
    const float* Wv_r, const float* bv_r, const float* ow_r, const float* ob_r, float* Wvo_r, float* bvo_r,
    const float* Wk_g, const float* bk_g, const float* q_g, u16* PkT_g, float* ck_g,
    const float* Wk_r, const float* bk_r, const float* q_r, u16* PkT_r, float* ck_r) {
  int j = blockIdx.x, e = threadIdx.x;
  if (blockIdx.y < 8) {
    int br = blockIdx.y >> 2, h = blockIdx.y & 3;
    const float* Wv = br ? Wv_r : Wv_g;  const float* bv = br ? bv_r : bv_g;
    const float* ow = br ? ow_r : ow_g;  const float* ob = br ? ob_r : ob_g;
    float* Wvo = br ? Wvo_r : Wvo_g;     float* bvo = br ? bvo_r : bvo_g;
    if (j < 128) {
      __shared__ float wrow[32];
      if (e < 32) wrow[e] = Wv[j * 128 + h * 32 + e];
      __syncthreads();
      float acc = 0.f;
      for (int d = 0; d < 32; ++d) acc += wrow[d] * ow[(h * 32 + d) * 128 + e];
      Wvo[(h * 128 + j) * 128 + e] = acc;
    } else if (h == 0) {
      __shared__ float bbv[128];
      bbv[e] = bv[e];
      __syncthreads();
      float acc = ob[e];
      for (int m = 0; m < 128; ++m) acc += bbv[m] * ow[m * 128 + e];
      bvo[e] = acc;
    }
  } else {
    int y = blockIdx.y - 8;
    int br = y >> 2, b = y & 3;
    int hq = e;
    if (hq >= 96) return;
    const float* Wk = br ? Wk_r : Wk_g;  const float* bk = br ? bk_r : bk_g;
    const float* q  = br ? q_r  : q_g;
    u16* PkT = br ? PkT_r : PkT_g;       float* ck = br ? ck_r : ck_g;
    int h = hq / 24, t = hq % 24;
    const float* qrow = q + (b * 24 + t) * 128 + h * 32;
    if (j < 128) {
      const float* wrow = Wk + j * 128 + h * 32;
      float acc = 0.f;
      for (int d = 0; d < 32; ++d) acc += wrow[d] * qrow[d];
      PkT[((size_t)b * 96 + hq) * 136 + j] = f2bf(acc * INV_SCALE);
    } else {
      float acc = 0.f;
      for (int d = 0; d < 32; ++d) acc += bk[h * 32 + d] * qrow[d];
      ck[b * 96 + hq] = acc * INV_SCALE;
    }
  }
}

// W1c[c][din] bf16 : c<128 -> w1k col c ; c>=128 -> w1v col c-128
__global__ __launch_bounds__(128) void k_w1c(
    const float* gk_w1, const float* gv_w1, const float* rk_w1, const float* rv_w1,
    u16* W1c_g, u16* W1c_r) {
  int c = blockIdx.x, br = blockIdx.y, d = threadIdx.x;
  int DIN = br ? 128 : 64;
  if (d >= DIN) return;
  const float* src = br ? (c < 128 ? rk_w1 : rv_w1) : (c < 128 ? gk_w1 : gv_w1);
  u16* dst = br ? W1c_r : W1c_g;
  dst[c * DIN + d] = f2bf(src[d * 128 + (c & 127)]);
}

// peB = bf16(pe_w)  (128 x 8192, same layout)
__global__ __launch_bounds__(256) void k_cvt(const float* __restrict__ src,
                                             u16* __restrict__ dst) {
  int i = (blockIdx.x * 256 + threadIdx.x) * 4;
  float4 v = *(const float4*)(src + i);
  uint2 o; o.x = pk2(v.x, v.y); o.y = pk2(v.z, v.w);
  *(uint2*)&dst[i] = o;
}

// ---------------- fused flash attention, bf16 MFMA ---------------------------
// 4 waves/block. Tiles of 64 keys; Xt double-buffered; 4 barriers/tile.
// NRED>1: staging sums NRED split-K partials (stride rstride) + bias[din].

template <int DIN, int NRED>
__global__ __launch_bounds__(256, 2) void k_flash(
    const float* __restrict__ X, const float* __restrict__ redbias, size_t rstride,
    const u16* __restrict__ W1c,            // [256][DIN] bf16 (k cols | v cols)
    const float* __restrict__ b1k, const float* __restrict__ b1v,
    const u16* __restrict__ PkT,            // [b][96][136] bf16
    const float* __restrict__ ck,           // [b][96]
    float* __restrict__ accP, float* __restrict__ lP,
    int KL, int kpb) {
  constexpr int KS = DIN / 32;
  constexpr int PD = DIN + 8;
  constexpr int PH = 136, PV = 72, PP = 72;
  constexpr int NR = DIN / 16;              // float4 loads per thread per tile
  int b = blockIdx.y, chunk = blockIdx.x, nchunk = gridDim.x;
  int t = threadIdx.x;
  int l = t & 63, w = t >> 6;
  int l16 = l & 15, l4 = l >> 4;

  __shared__ __align__(16) u16 Xt[2][64 * PD];
  __shared__ __align__(16) u16 HB[9216];        // Hk[64][136] / HvT[128][72]
  __shared__ __align__(16) u16 Pt[96 * PP];
  __shared__ __align__(16) u16 Pk_s[96 * 136];
  __shared__ float lred[384];

  const float* Xb = X + (size_t)b * KL * DIN + (size_t)chunk * kpb * DIN;

  // stage PkT[b] into LDS (once per block)
  {
    const unsigned* ps = (const unsigned*)(PkT + (size_t)b * 96 * 136);
    unsigned* pd = (unsigned*)Pk_s;
    for (int i = t; i < 96 * 136 / 2; i += 256) pd[i] = ps[i];
  }

  // persistent register fragments
  bf8 wkA[2][KS], wvB[2][KS];
#pragma unroll
  for (int m = 0; m < 2; ++m)
#pragma unroll
    for (int ks = 0; ks < KS; ++ks) {
      int hid = w * 32 + m * 16 + l16;
      wkA[m][ks] = *(const bf8*)(W1c + (size_t)hid * DIN + ks * 32 + l4 * 8);
      wvB[m][ks] = *(const bf8*)(W1c + (size_t)(128 + hid) * DIN + ks * 32 + l4 * 8);
    }
  float bkA[2][4], bvB[2], ckr[6];
#pragma unroll
  for (int m = 0; m < 2; ++m)
#pragma unroll
    for (int r = 0; r < 4; ++r) bkA[m][r] = b1k[w * 32 + m * 16 + l4 * 4 + r];
#pragma unroll
  for (int n = 0; n < 2; ++n) bvB[n] = b1v[w * 32 + n * 16 + l16];
#pragma unroll
  for (int n = 0; n < 6; ++n) ckr[n] = ck[b * 96 + n * 16 + l16];

  f4v accO[6][2];
#pragma unroll
  for (int m = 0; m < 6; ++m)
#pragma unroll
    for (int n = 0; n < 2; ++n) accO[m][n] = (f4v){0.f, 0.f, 0.f, 0.f};
  float lacc[6] = {0.f, 0.f, 0.f, 0.f, 0.f, 0.f};

  float4 xr[NR];
  auto load_tile = [&](int kt) {
    const float* Xrow = Xb + (size_t)kt * 64 * DIN;
#pragma unroll
    for (int r = 0; r < NR; ++r) {
      int idx = (r * 256 + t) * 4;
      if constexpr (NRED == 1) {
        xr[r] = *(const float4*)(Xrow + idx);
      } else {
        int din = idx % DIN;
        float4 a = *(const float4*)(redbias + din);
#pragma unroll
        for (int c = 0; c < NRED; ++c) {
          float4 v = *(const float4*)(Xrow + (size_t)c * rstride + idx);
          a.x += v.x; a.y += v.y; a.z += v.z; a.w += v.w;
        }
        xr[r] = a;
      }
    }
  };

  int ntile = kpb >> 6;
  load_tile(0);
  int buf = 0;
  for (int kt = 0; kt < ntile; ++kt) {
    // ---- write staged tile (regs -> LDS bf16), prefetch next ----
#pragma unroll
    for (int r = 0; r < NR; ++r) {
      int idx = (r * 256 + t) * 4;
      int key = idx / DIN, din = idx % DIN;
      uint2 o; o.x = pk2(xr[r].x, xr[r].y); o.y = pk2(xr[r].z, xr[r].w);
      *(uint2*)&Xt[buf][key * PD + din] = o;
    }
    if (kt + 1 < ntile) load_tile(kt + 1);
    __syncthreads();                                   // b1

    // ---- G1a: Hk = W1k^T @ X^T  (M=hid 32/wave, N=64 keys) ----
    {
      f4v hk[2][4];
#pragma unroll
      for (int m = 0; m < 2; ++m)
#pragma unroll
        for (int n = 0; n < 4; ++n) hk[m][n] = (f4v){0.f, 0.f, 0.f, 0.f};
#pragma unroll
      for (int ks = 0; ks < KS; ++ks) {
        bf8 xf[4];
#pragma unroll
        for (int n = 0; n < 4; ++n)
          xf[n] = *(const bf8*)&Xt[buf][(n * 16 + l16) * PD + ks * 32 + l4 * 8];
#pragma unroll
        for (int m = 0; m < 2; ++m)
#pragma unroll
          for (int n = 0; n < 4; ++n) hk[m][n] = MFMA16(wkA[m][ks], xf[n], hk[m][n]);
      }
#pragma unroll
      for (int m = 0; m < 2; ++m)
#pragma unroll
        for (int n = 0; n < 4; ++n) {
          int key = n * 16 + l16;
          int hid0 = w * 32 + m * 16 + l4 * 4;
          float v0 = fmaxf(hk[m][n][0] + bkA[m][0], 0.f);
          float v1 = fmaxf(hk[m][n][1] + bkA[m][1], 0.f);
          float v2 = fmaxf(hk[m][n][2] + bkA[m][2], 0.f);
          float v3 = fmaxf(hk[m][n][3] + bkA[m][3], 0.f);
          uint2 o; o.x = pk2(v0, v1); o.y = pk2(v2, v3);
          *(uint2*)&HB[key * PH + hid0] = o;
        }
    }
    __syncthreads();                                   // b2

    // ---- G2: S = Hk @ Pk (wave's 16 keys x 96 hq, K=128) ----
    {
      f4v sa[6];
#pragma unroll
      for (int n = 0; n < 6; ++n) sa[n] = (f4v){ckr[n], ckr[n], ckr[n], ckr[n]};
#pragma unroll
      for (int ks = 0; ks < 4; ++ks) {
        bf8 a = *(const bf8*)&HB[(w * 16 + l16) * PH + ks * 32 + l4 * 8];
#pragma unroll
        for (int n = 0; n < 6; ++n) {
          bf8 bp = *(const bf8*)&Pk_s[(n * 16 + l16) * 136 + ks * 32 + l4 * 8];
          sa[n] = MFMA16(a, bp, sa[n]);
        }
      }
#pragma unroll
      for (int n = 0; n < 6; ++n) {
        float e0 = __expf(sa[n][0]), e1 = __expf(sa[n][1]);
        float e2 = __expf(sa[n][2]), e3 = __expf(sa[n][3]);
        float ls = (e0 + e1) + (e2 + e3);
        ls += __shfl_xor(ls, 16);
        ls += __shfl_xor(ls, 32);
        lacc[n] += ls;
        uint2 o; o.x = pk2(e0, e1); o.y = pk2(e2, e3);
        *(uint2*)&Pt[(n * 16 + l16) * PP + w * 16 + l4 * 4] = o;
      }
    }
    __syncthreads();                                   // b3 (Hk dead, Pt ready)

    // ---- G1b: Hv = X @ W1v -> HvT[hid][key] ----
    {
      f4v hv[4][2];
#pragma unroll
      for (int m = 0; m < 4; ++m)
#pragma unroll
        for (int n = 0; n < 2; ++n) hv[m][n] = (f4v){0.f, 0.f, 0.f, 0.f};
#pragma unroll
      for (int ks = 0; ks < KS; ++ks) {
        bf8 xa[4];
#pragma unroll
        for (int m = 0; m < 4; ++m)
          xa[m] = *(const bf8*)&Xt[buf][(m * 16 + l16) * PD + ks * 32 + l4 * 8];
#pragma unroll
        for (int m = 0; m < 4; ++m)
#pragma unroll
          for (int n = 0; n < 2; ++n) hv[m][n] = MFMA16(xa[m], wvB[n][ks], hv[m][n]);
      }
#pragma unroll
      for (int m = 0; m < 4; ++m)
#pragma unroll
        for (int n = 0; n < 2; ++n) {
          int d = w * 32 + n * 16 + l16;
          int key0 = m * 16 + l4 * 4;
          float v0 = fmaxf(hv[m][n][0] + bvB[n], 0.f);
          float v1 = fmaxf(hv[m][n][1] + bvB[n], 0.f);
          float v2 = fmaxf(hv[m][n][2] + bvB[n], 0.f);
          float v3 = fmaxf(hv[m][n][3] + bvB[n], 0.f);
          uint2 o; o.x = pk2(v0, v1); o.y = pk2(v2, v3);
          *(uint2*)&HB[d * PV + key0] = o;
        }
    }
    __syncthreads();                                   // b4 (HvT ready)

    // ---- G3: ACC += P^T @ Hv  (M=96 hq, N=d 32/wave, K=64 keys) ----
#pragma unroll
    for (int ks = 0; ks < 2; ++ks) {
      bf8 pa[6];
#pragma unroll
      for (int m = 0; m < 6; ++m)
        pa[m] = *(const bf8*)&Pt[(m * 16 + l16) * PP + ks * 32 + l4 * 8];
#pragma unroll
      for (int n = 0; n < 2; ++n) {
        bf8 hb = *(const bf8*)&HB[(w * 32 + n * 16 + l16) * PV + ks * 32 + l4 * 8];
#pragma unroll
        for (int m = 0; m < 6; ++m) accO[m][n] = MFMA16(pa[m], hb, accO[m][n]);
      }
    }
    buf ^= 1;
    // no trailing barrier: next write targets the other Xt buffer; b1 orders HB/Pt.
  }

  // ---- write partial ACC (96x128 fp32) and partial l (96) ----
  float* ap = accP + (size_t)(b * nchunk + chunk) * 96 * 128;
#pragma unroll
  for (int m = 0; m < 6; ++m)
#pragma unroll
    for (int n = 0; n < 2; ++n) {
      int d = w * 32 + n * 16 + l16;
#pragma unroll
      for (int r = 0; r < 4; ++r) {
        int hq = m * 16 + l4 * 4 + r;
        ap[hq * 128 + d] = accO[m][n][r];
      }
    }
  if (l4 == 0) {
#pragma unroll
    for (int n = 0; n < 6; ++n) lred[w * 96 + n * 16 + l16] = lacc[n];
  }
  __syncthreads();
  if (t < 96) {
    float s = lred[t] + lred[96 + t] + lred[192 + t] + lred[288 + t];
    lP[(size_t)(b * nchunk + chunk) * 96 + t] = s;
  }
}

// ---------------- patch conv, bf16 MFMA (split-K 8, swizzled Wt) -------------
// grid (96 bt, 8 kc); 16 channels per kc; K-step = 2 channels (128).

__global__ __launch_bounds__(256, 3) void k_patch(const float* __restrict__ X,
    const u16* __restrict__ peB, float* __restrict__ patchP) {
  int bt = blockIdx.x, kc = blockIdx.y;
  int t = threadIdx.x;
  int l = t & 63, w = t >> 6;
  int l16 = l & 15, l4 = l >> 4;
  const float* Xbt = X + (size_t)bt * 524288 + (size_t)kc * 65536;

  __shared__ __align__(16) u16 Xp[64 * 136];
  __shared__ __align__(16) u16 Wt[128 * 128];   // XOR-swizzled: slot ^= co&7

  f4v acc[4][2];
#pragma unroll
  for (int m = 0; m < 4; ++m)
#pragma unroll
    for (int n = 0; n < 2; ++n) acc[m][n] = (f4v){0.f, 0.f, 0.f, 0.f};

  float4 xr[8];
  auto loadX = [&](int s) {
    const float* img = Xbt + (size_t)s * 8192;
#pragma unroll
    for (int r = 0; r < 8; ++r) xr[r] = *(const float4*)(img + (r * 256 + t) * 4);
  };
  loadX(0);

  for (int s = 0; s < 8; ++s) {
    // X: regs -> LDS (patch-major, pitch 136)
#pragma unroll
    for (int r = 0; r < 8; ++r) {
      int idx = (r * 256 + t) * 4;
      int cl = idx >> 12, off = idx & 4095;
      int h = off >> 6, w0 = off & 63;
      int patch = (h >> 3) * 8 + (w0 >> 3);
      int within = (h & 7) * 8 + (w0 & 7);
      uint2 o; o.x = pk2(xr[r].x, xr[r].y); o.y = pk2(xr[r].z, xr[r].w);
      *(uint2*)&Xp[patch * 136 + cl * 64 + within] = o;
    }
    // W: global (L2-hot bf16) -> LDS, swizzled
    {
      int colbase = kc * 1024 + s * 128;
#pragma unroll
      for (int r = 0; r < 8; ++r) {
        int idx = r * 256 + t;
        int co = idx >> 4, part = idx & 15;
        int slot = part ^ (co & 7);
        uint4 v = *(const uint4*)(peB + (size_t)co * 8192 + colbase + part * 8);
        *(uint4*)&Wt[co * 128 + slot * 8] = v;
      }
    }
    if (s < 7) loadX(s + 1);
    __syncthreads();
#pragma unroll
    for (int ks2 = 0; ks2 < 4; ++ks2) {
      bf8 af[4];
#pragma unroll
      for (int m = 0; m < 4; ++m)
        af[m] = *(const bf8*)&Xp[(m * 16 + l16) * 136 + ks2 * 32 + l4 * 8];
#pragma unroll
      for (int n = 0; n < 2; ++n) {
        int co = w * 32 + n * 16 + l16;
        int slot = (ks2 * 4 + l4) ^ (co & 7);
        bf8 bf_ = *(const bf8*)&Wt[co * 128 + slot * 8];
#pragma unroll
        for (int m = 0; m < 4; ++m) acc[m][n] = MFMA16(af[m], bf_, acc[m][n]);
      }
    }
    __syncthreads();
  }
  float* outp = patchP + ((size_t)kc * 6144 + bt * 64) * 128;
#pragma unroll
  for (int m = 0; m < 4; ++m)
#pragma unroll
    for (int n = 0; n < 2; ++n) {
      int d = w * 32 + n * 16 + l16;
#pragma unroll
      for (int r = 0; r < 4; ++r) {
        int patch = m * 16 + l4 * 4 + r;
        outp[patch * 128 + d] = acc[m][n][r];
      }
    }
}

__global__ __launch_bounds__(256) void k_reduceacc(const float* __restrict__ accP,
    float* __restrict__ out, int nchunk) {
  int b = blockIdx.y;
  int idx = blockIdx.x * 256 + threadIdx.x;   // < 12288
  const float* p = accP + (size_t)b * nchunk * 12288 + idx;
  float a = 0.f;
  for (int c = 0; c < nchunk; ++c) a += p[(size_t)c * 12288];
  out[b * 12288 + idx] = a;
}

// og[b,t,:] = bvo + sum_h (acc[b,h*24+t,:]/l) @ Wvo[h]
__global__ __launch_bounds__(128) void k_og(const float* __restrict__ accR,
    const float* __restrict__ lP, int nchunk,
    const float* __restrict__ Wvo, const float* __restrict__ bvo,
    float* __restrict__ og) {
  int row = blockIdx.x;  int b = row / 24, tq = row % 24;
  int e = threadIdx.x;
  __shared__ float invl[4];
  __shared__ float op[4 * 128];
  if (e < 4) {
    int hq = e * 24 + tq;
    float lsum = 0.f;
    const float* lp = lP + (size_t)b * nchunk * 96 + hq;
    for (int c = 0; c < nchunk; ++c) lsum += lp[(size_t)c * 96];
    invl[e] = 1.f / lsum;
  }
  __syncthreads();
  for (int h = 0; h < 4; ++h)
    op[h * 128 + e] = accR[(size_t)(b * 96 + h * 24 + tq) * 128 + e] * invl[h];
  __syncthreads();
  float acc = bvo[e];
  for (int h = 0; h < 4; ++h) {
    const float* ww = Wvo + h * 16384;
    const float* o = op + h * 128;
    for (int j = 0; j < 128; ++j) acc += o[j] * ww[j * 128 + e];
  }
  og[row * 128 + e] = acc;
}

// ---------------- output writers ---------------------------------------------

__global__ __launch_bounds__(256) void k_gout(const float* __restrict__ og,
                                              float* __restrict__ out) {
  int b = blockIdx.y;
  const float* ogb = og + b * 24 * 128;
  float* ob = out + (size_t)b * 6291456;
  for (int i4 = blockIdx.x * 256 + threadIdx.x; i4 < 1572864; i4 += gridDim.x * 256) {
    int i = i4 * 4;
    int n = i >> 7, e = i & 127;
    float src = fmaxf((n + 0.5f) * (1.f / 2048.f) - 0.5f, 0.f);
    int t0 = (int)src; float lam = src - (float)t0; int t1 = min(t0 + 1, 23);
    float4 a = *(const float4*)&ogb[t0 * 128 + e];
    float4 c = *(const float4*)&ogb[t1 * 128 + e];
    float4 o;
    o.x = a.x + lam * (c.x - a.x); o.y = a.y + lam * (c.y - a.y);
    o.z = a.z + lam * (c.z - a.z); o.w = a.w + lam * (c.w - a.w);
    *(float4*)&ob[i] = o;
  }
}

// U = og_r @ up_w : block owns 64 out-cols, og (48KB) in LDS, up_w read ONCE.
__global__ __launch_bounds__(256) void k_U(const float* __restrict__ og_r,
    const float* __restrict__ up_w, float* __restrict__ U) {
  int col = blockIdx.x * 64 + (threadIdx.x & 63);
  int rg = threadIdx.x >> 6;               // 4 row-groups x 24 rows
  __shared__ float og_s[96 * 128];
  for (int i = threadIdx.x; i < 96 * 128 / 4; i += 256)
    ((float4*)og_s)[i] = ((const float4*)og_r)[i];
  __syncthreads();
  float acc[24];
#pragma unroll
  for (int r = 0; r < 24; ++r) acc[r] = 0.f;
#pragma unroll 4
  for (int c = 0; c < 128; ++c) {
    float wv = up_w[(size_t)c * 8192 + col];
#pragma unroll
    for (int r = 0; r < 24; ++r) acc[r] += og_s[(rg * 24 + r) * 128 + c] * wv;
  }
#pragma unroll
  for (int r = 0; r < 24; ++r) U[(size_t)(rg * 24 + r) * 8192 + col] = acc[r];
}

__global__ __launch_bounds__(256) void k_up(const float* __restrict__ U,
    const float* __restrict__ up_b, float* __restrict__ out) {
  for (int i4 = blockIdx.x * 256 + threadIdx.x; i4 < 12582912; i4 += gridDim.x * 256) {
    int i = i4 * 4;
    int w0 = i & 63;
    int h  = (i >> 6) & 63;
    int o  = (i >> 12) & 127;
    int bt = i >> 19;                 // 0..95
    int b = bt / 24, tt = bt - b * 24;
    int ii = h >> 3, p = h & 7, j = w0 >> 3, q0 = w0 & 7;
    int n = tt * 64 + ii * 8 + j;
    float src = fmaxf((n + 0.5f) * (1.f / 64.f) - 0.5f, 0.f);
    int t0 = (int)src; float lam = src - (float)t0; int t1 = min(t0 + 1, 23);
    const float* u0 = U + (size_t)(b * 24 + t0) * 8192 + o * 64 + p * 8 + q0;
    const float* u1 = U + (size_t)(b * 24 + t1) * 8192 + o * 64 + p * 8 + q0;
    float bb = up_b[o];
    float4 a = *(const float4*)u0, c = *(const float4*)u1;
    float4 r;
    r.x = a.x + lam * (c.x - a.x) + bb; r.y = a.y + lam * (c.y - a.y) + bb;
    r.z = a.z + lam * (c.z - a.z) + bb; r.w = a.w + lam * (c.w - a.w) + bb;
    *(float4*)&out[i] = r;
  }
}

// ---------------------------------------------------------------------------

extern "C" void kernel_launch(void* const* d_in, const int* in_sizes, int n_in,
                              void* d_out, int out_size, void* d_ws, size_t ws_size,
                              hipStream_t stream) {
  (void)in_sizes; (void)n_in; (void)out_size; (void)ws_size;
  const float* gf    = (const float*)d_in[0];
  const float* gridf = (const float*)d_in[1];
  const float* gti   = (const float*)d_in[2];
  const float* gek_w1 = (const float*)d_in[4],  *gek_b1 = (const float*)d_in[5];
  const float* gek_w2 = (const float*)d_in[6],  *gek_b2 = (const float*)d_in[7];
  const float* gev_w1 = (const float*)d_in[8],  *gev_b1 = (const float*)d_in[9];
  const float* gev_w2 = (const float*)d_in[10], *gev_b2 = (const float*)d_in[11];
  const float* rk_w1  = (const float*)d_in[12], *rk_b1  = (const float*)d_in[13];
  const float* rk_w2  = (const float*)d_in[14], *rk_b2  = (const float*)d_in[15];
  const float* rv_w1  = (const float*)d_in[16], *rv_b1  = (const float*)d_in[17];
  const float* rv_w2  = (const float*)d_in[18], *rv_b2  = (const float*)d_in[19];
  const float* te_w1  = (const float*)d_in[20], *te_b1  = (const float*)d_in[21];
  const float* te_w2  = (const float*)d_in[22], *te_b2  = (const float*)d_in[23];
  const float* pe_w   = (const float*)d_in[24], *pe_b   = (const float*)d_in[25];
  const float* up_w   = (const float*)d_in[26], *up_b   = (const float*)d_in[27];
  const float* ag_q_w = (const float*)d_in[28], *ag_q_b = (const float*)d_in[29];
  const float* ag_k_w = (const float*)d_in[30], *ag_k_b = (const float*)d_in[31];
  const float* ag_v_w = (const float*)d_in[32], *ag_v_b = (const float*)d_in[33];
  const float* ag_o_w = (const float*)d_in[34], *ag_o_b = (const float*)d_in[35];
  const float* ar_q_w = (const float*)d_in[36], *ar_q_b = (const float*)d_in[37];
  const float* ar_k_w = (const float*)d_in[38], *ar_k_b = (const float*)d_in[39];
  const float* ar_v_w = (const float*)d_in[40], *ar_v_b = (const float*)d_in[41];
  const float* ar_o_w = (const float*)d_in[42], *ar_o_b = (const float*)d_in[43];

  float* out = (float*)d_out;          // g_out (25165824 f) then up (50331648 f)
  float* ws = (float*)d_ws;
  size_t off = 0;
  auto A = [&](size_t n) { float* p = ws + off; off += n; return p; };
  float* q_g   = A(12288);   float* q_r   = A(12288);
  float* Wk_g  = A(16384);   float* bk_g  = A(128);
  float* Wv_g  = A(16384);   float* bv_g  = A(128);
  float* Wk_r  = A(16384);   float* bk_r  = A(128);
  float* Wv_r  = A(16384);   float* bv_r  = A(128);
  float* Wvo_g = A(65536);   float* bvo_g = A(128);
  float* Wvo_r = A(65536);   float* bvo_r = A(128);
  float* ck_g  = A(384);     float* ck_r  = A(384);
  u16*   PkT_g = (u16*)A(26112);   // 96*136 bf16 * 4 batches? no: [b][96][136] => 4*96*136/2 f
  u16*   PkT_r = (u16*)A(26112);
  u16*   W1c_g = (u16*)A(8192);    // 256*64 bf16
  u16*   W1c_r = (u16*)A(16384);   // 256*128 bf16
  u16*   peB   = (u16*)A(524288);  // 128*8192 bf16
  float* lP_g  = A(49152);   float* lP_r  = A(9216);
  float* accG  = A(49152);   float* accR2 = A(49152);
  float* og_g  = A(12288);   float* og_r  = A(12288);
  float* accP_r = A(1179648);      // 4*24*12288
  float* U      = A(786432);
  float* BIG   = A(6291456);       // accP_g (4*128*12288) then patchP (8*6144*128)
  float* accP_g = BIG;
  float* patchP = BIG;
  // total ~9.3M floats (~37 MB)

  k_w1c<<<dim3(256, 2), 128, 0, stream>>>(gek_w1, gev_w1, rk_w1, rv_w1, W1c_g, W1c_r);
  k_cvt<<<1024, 256, 0, stream>>>(pe_w, peB);
  k_teq<<<96, 128, 0, stream>>>(gti, te_w1, te_b1, te_w2, te_b2,
                                ag_q_w, ag_q_b, ar_q_w, ar_q_b, q_g, q_r);
  k_fold<<<dim3(129, 4), 128, 0, stream>>>(
      gek_w2, gek_b2, ag_k_w, ag_k_b, Wk_g, bk_g,
      gev_w2, gev_b2, ag_v_w, ag_v_b, Wv_g, bv_g,
      rk_w2,  rk_b2,  ar_k_w, ar_k_b, Wk_r, bk_r,
      rv_w2,  rv_b2,  ar_v_w, ar_v_b, Wv_r, bv_r);
  k_wvopk<<<dim3(129, 16), 128, 0, stream>>>(
      Wv_g, bv_g, ag_o_w, ag_o_b, Wvo_g, bvo_g,
      Wv_r, bv_r, ar_o_w, ar_o_b, Wvo_r, bvo_r,
      Wk_g, bk_g, q_g, PkT_g, ck_g,
      Wk_r, bk_r, q_r, PkT_r, ck_r);

  // graph branch: 49152 keys/batch, 128 chunks x 384 keys (6 tiles of 64)
  k_flash<64, 1><<<dim3(128, 4), 256, 0, stream>>>(
      gf, (const float*)nullptr, 0, W1c_g, gek_b1, gev_b1, PkT_g, ck_g,
      accP_g, lP_g, 49152, 384);
  k_reduceacc<<<dim3(48, 4), 256, 0, stream>>>(accP_g, accG, 128);
  k_og<<<96, 128, 0, stream>>>(accG, lP_g, 128, Wvo_g, bvo_g, og_g);
  k_gout<<<dim3(1024, 4), 256, 0, stream>>>(og_g, out);

  // grid branch: patch conv (split-K 8), flash consumes partials directly
  k_patch<<<dim3(96, 8), 256, 0, stream>>>(gridf, peB, patchP);
  k_flash<128, 8><<<dim3(24, 4), 256, 0, stream>>>(
      patchP, pe_b, 786432, W1c_r, rk_b1, rv_b1, PkT_r, ck_r,
      accP_r, lP_r, 1536, 64);
  k_reduceacc<<<dim3(48, 4), 256, 0, stream>>>(accP_r, accR2, 24);
  k_og<<<96, 128, 0, stream>>>(accR2, lP_r, 24, Wvo_r, bvo_r, og_r);
  k_U<<<128, 256, 0, stream>>>(og_r, up_w, U);
  k_up<<<4096, 256, 0, stream>>>(U, up_b, out + 25165824);
}